// Round 12
// baseline (93.687 us; speedup 1.0000x reference)
//
#include <hip/hip_runtime.h>

#define BB 4
#define SS 2048
#define HH 8
#define MM 16

// 0.25 (= 1/sqrt(16)) * log2(e): fold softmax scale + exp->exp2 conversion into Q
#define QSCALE 0.36067376022224085f

typedef __attribute__((ext_vector_type(8)))  short short8;
typedef __attribute__((ext_vector_type(4)))  int   int4v;
typedef __attribute__((ext_vector_type(4)))  float f32x4;
typedef __attribute__((ext_vector_type(16))) float f32x16;

static constexpr size_t NQKV = (size_t)BB * HH * SS * MM;  // 1,048,576 elements

__device__ __forceinline__ int pk_bf16(float lo, float hi) {
    int r;
    asm("v_cvt_pk_bf16_f32 %0, %1, %2" : "=v"(r) : "v"(lo), "v"(hi));
    return r;
}

// ---------------- Kernel 1: Q/K/V projections (writes bf16, row-major) -------
__device__ __forceinline__ void proj16(const float xr[16], const float* __restrict__ w,
                                       const float* __restrict__ bias, int h, float out[16]) {
#pragma unroll
    for (int i = 0; i < 16; i++) out[i] = bias[(h << 4) + i];
#pragma unroll
    for (int j = 0; j < 16; j++) {
        float xj = xr[j];
        const float* wr = w + (((j * HH) + h) << 4);
#pragma unroll
        for (int i = 0; i < 16; i++) out[i] = fmaf(xj, wr[i], out[i]);
    }
}

__device__ __forceinline__ void pack_store(ushort* dst, const float o[16], float scale) {
    int4v w0, w1;
#pragma unroll
    for (int j = 0; j < 4; j++) w0[j] = pk_bf16(o[2*j] * scale,     o[2*j+1] * scale);
#pragma unroll
    for (int j = 0; j < 4; j++) w1[j] = pk_bf16(o[8+2*j] * scale,   o[8+2*j+1] * scale);
    int4v* p = (int4v*)dst;
    p[0] = w0; p[1] = w1;
}

__global__ __launch_bounds__(256) void proj_kernel(
    const float* __restrict__ x,
    const float* __restrict__ wq, const float* __restrict__ bq,
    const float* __restrict__ wk, const float* __restrict__ bk,
    const float* __restrict__ wv, const float* __restrict__ bv,
    ushort* __restrict__ qb, ushort* __restrict__ kb, ushort* __restrict__ vb)
{
    // 256 blocks: h = blockIdx>>5 (uniform -> scalar-cached weights)
    int h  = blockIdx.x >> 5;
    int bs = ((blockIdx.x & 31) << 8) + threadIdx.x;   // b*S + s
    int b  = bs >> 11;

    float xr[16];
    const float4* x4 = (const float4*)(x + (size_t)bs * MM);
#pragma unroll
    for (int j = 0; j < 4; j++) {
        float4 t = x4[j];
        xr[j*4+0] = t.x; xr[j*4+1] = t.y; xr[j*4+2] = t.z; xr[j*4+3] = t.w;
    }

    size_t orow = (((size_t)(b * HH + h) * SS) + (bs & 2047)) * MM;
    float o[16];

    proj16(xr, wq, bq, h, o);  pack_store(qb + orow, o, QSCALE);
    proj16(xr, wk, bk, h, o);  pack_store(kb + orow, o, 1.0f);
    proj16(xr, wv, bv, h, o);  pack_store(vb + orow, o, 1.0f);
}

// ---------------- Kernel 2: MFMA flash attention (6 waves/SIMD target) -------
// 1024 blocks x 512 thr; block = 64 queries (2 qw) x 4 K-groups (512 keys).
// LDS 51.2 KB (<53.3) -> 3 blocks/CU; __launch_bounds__(512,6) caps VGPR at 85
// -> 24 waves/CU = 6 waves/SIMD: stalls of one block hide under the other two.
// Per grp: single-buffered 128-key tile, reg-carry prefetch (T14), 2 barriers
// per tile. K stored split-half (c*1024 + key*8 shorts: 16 B rows); V^T rows
// 0-15 scatter-staged at stride 136; rows 16,20 = ones (l rows), 17-19/21-31
// zero. NUMERICS: PV feeds P-1 (p near 1 -> ~5x less bf16 abs err); missing
// V*1 term = per-tile V column sums merged in epilogue; l correction = +2048.
__global__ __launch_bounds__(512, 6) void attn_kernel(
    const ushort* __restrict__ qb, const ushort* __restrict__ kb,
    const ushort* __restrict__ vb, float* __restrict__ hb)
{
    // per grp: K split-half [0..2047], V^T 32x136 [2048..6399]. 4x12800 B.
    __shared__ ushort stage[4][6400];

    int tid = threadIdx.x;
    int w = tid >> 6, grp = w >> 1, qw = w & 1;
    int lane = tid & 63;
    int n = lane & 31, c = lane >> 5;
    int t7 = tid & 127;           // thread index within the grp's 2 waves

    // XCD-aware swizzle (1024 = 8 x 128, bijective)
    int nb = ((blockIdx.x & 7) << 7) | (blockIdx.x >> 3);
    int bh = nb >> 5, qt = nb & 31;
    size_t base = (size_t)bh * SS * MM;
    const ushort* Qg = qb + base;
    const ushort* Kg = kb + base;
    const ushort* Vg = vb + base;

    int q = qt * 64 + qw * 32 + n;
    short8 qf = *(const short8*)(Qg + (size_t)q * MM + c * 8);

    ushort* Kl = &stage[grp][0];
    ushort* Vt = &stage[grp][2048];

    // init V^T rows 16..31: 16,20 = ones (l rows), rest zero
    for (int i = t7; i < 136; i += 128) {
        Vt[16 * 136 + i] = 0x3F80;
        Vt[20 * 136 + i] = 0x3F80;
#pragma unroll
        for (int r = 17; r < 20; r++) Vt[r * 136 + i] = 0;
#pragma unroll
        for (int r = 21; r < 32; r++) Vt[r * 136 + i] = 0;
    }

    int k0 = grp * 512;
    int srow = t7;                // each grp thread stages one key row per tile

    // prologue: stage tile 0
    {
        const ushort* kr = Kg + (size_t)(k0 + srow) * MM;
        const ushort* vr = Vg + (size_t)(k0 + srow) * MM;
        int4v kw0 = *(const int4v*)(kr);
        int4v kw1 = *(const int4v*)(kr + 8);
        int4v vw0 = *(const int4v*)(vr);
        int4v vw1 = *(const int4v*)(vr + 8);
        *(int4v*)&Kl[srow * 8]        = kw0;   // half c=0
        *(int4v*)&Kl[1024 + srow * 8] = kw1;   // half c=1
        union { int4v v; ushort s[8]; } ua, ub; ua.v = vw0; ub.v = vw1;
#pragma unroll
        for (int j = 0; j < 8; j++) Vt[j * 136 + srow]       = ua.s[j];
#pragma unroll
        for (int j = 0; j < 8; j++) Vt[(8 + j) * 136 + srow] = ub.s[j];
    }
    __syncthreads();

    f32x16 oacc = 0;
    const f32x16 zacc = 0;
    float cs = 0.0f;              // V column-sum partial (this wave's qw half)
    int csd = lane >> 2, csp = lane & 3;

    for (int t = 0; t < 4; t++) {
        // prefetch next tile into regs; latency hides under this tile's compute
        int4v kw0, kw1, vw0, vw1;
        if (t != 3) {
            const ushort* kr = Kg + (size_t)(k0 + (t + 1) * 128 + srow) * MM;
            const ushort* vr = Vg + (size_t)(k0 + (t + 1) * 128 + srow) * MM;
            kw0 = *(const int4v*)(kr);
            kw1 = *(const int4v*)(kr + 8);
            vw0 = *(const int4v*)(vr);
            vw1 = *(const int4v*)(vr + 8);
        }

#pragma unroll
        for (int sub = 0; sub < 4; sub++) {
            short8 kf  = *(const short8*)&Kl[c * 1024 + (sub * 32 + n) * 8];
            short8 vf1 = *(const short8*)&Vt[n * 136 + sub * 32 + c * 8];
            short8 vf2 = *(const short8*)&Vt[n * 136 + sub * 32 + 16 + c * 8];

            f32x16 s = __builtin_amdgcn_mfma_f32_32x32x16_bf16(kf, qf, zacc, 0, 0, 0);

            float p0 = __builtin_amdgcn_exp2f(s[0])  - 1.0f;
            float p1 = __builtin_amdgcn_exp2f(s[1])  - 1.0f;
            float p2 = __builtin_amdgcn_exp2f(s[2])  - 1.0f;
            float p3 = __builtin_amdgcn_exp2f(s[3])  - 1.0f;
            float p4 = __builtin_amdgcn_exp2f(s[4])  - 1.0f;
            float p5 = __builtin_amdgcn_exp2f(s[5])  - 1.0f;
            float p6 = __builtin_amdgcn_exp2f(s[6])  - 1.0f;
            float p7 = __builtin_amdgcn_exp2f(s[7])  - 1.0f;
            int a0 = pk_bf16(p0, p1), a1 = pk_bf16(p2, p3);
            int a2 = pk_bf16(p4, p5), a3 = pk_bf16(p6, p7);
            int w0 = a0, w2 = a2;
            asm("v_permlane32_swap_b32 %0, %1" : "+v"(w0), "+v"(w2));
            int w1 = a1, w3 = a3;
            asm("v_permlane32_swap_b32 %0, %1" : "+v"(w1), "+v"(w3));
            int4v bi1 = {w0, w1, w2, w3};
            oacc = __builtin_amdgcn_mfma_f32_32x32x16_bf16(
                vf1, __builtin_bit_cast(short8, bi1), oacc, 0, 0, 0);

            float p8  = __builtin_amdgcn_exp2f(s[8])  - 1.0f;
            float p9  = __builtin_amdgcn_exp2f(s[9])  - 1.0f;
            float p10 = __builtin_amdgcn_exp2f(s[10]) - 1.0f;
            float p11 = __builtin_amdgcn_exp2f(s[11]) - 1.0f;
            float p12 = __builtin_amdgcn_exp2f(s[12]) - 1.0f;
            float p13 = __builtin_amdgcn_exp2f(s[13]) - 1.0f;
            float p14 = __builtin_amdgcn_exp2f(s[14]) - 1.0f;
            float p15 = __builtin_amdgcn_exp2f(s[15]) - 1.0f;
            int a4 = pk_bf16(p8,  p9),  a5 = pk_bf16(p10, p11);
            int a6 = pk_bf16(p12, p13), a7 = pk_bf16(p14, p15);
            int u0 = a4, u2 = a6;
            asm("v_permlane32_swap_b32 %0, %1" : "+v"(u0), "+v"(u2));
            int u1 = a5, u3 = a7;
            asm("v_permlane32_swap_b32 %0, %1" : "+v"(u1), "+v"(u3));
            int4v bi2 = {u0, u1, u2, u3};
            oacc = __builtin_amdgcn_mfma_f32_32x32x16_bf16(
                vf2, __builtin_bit_cast(short8, bi2), oacc, 0, 0, 0);
        }

        // per-tile V column sum: wave qw covers keys qw*64 + csp*16 .. +15
        {
            const ushort* vrow = &Vt[csd * 136 + qw * 64 + csp * 16];
            int4v u0 = *(const int4v*)(vrow);
            int4v u1 = *(const int4v*)(vrow + 8);
#pragma unroll
            for (int j = 0; j < 4; j++) {
                cs += __builtin_bit_cast(float, u0[j] << 16);
                cs += __builtin_bit_cast(float, (int)(u0[j] & 0xFFFF0000));
                cs += __builtin_bit_cast(float, u1[j] << 16);
                cs += __builtin_bit_cast(float, (int)(u1[j] & 0xFFFF0000));
            }
        }

        __syncthreads();          // all grp waves done reading tile t
        if (t != 3) {
            *(int4v*)&Kl[srow * 8]        = kw0;
            *(int4v*)&Kl[1024 + srow * 8] = kw1;
            union { int4v v; ushort s[8]; } ua, ub; ua.v = vw0; ub.v = vw1;
#pragma unroll
            for (int j = 0; j < 8; j++) Vt[j * 136 + srow]       = ua.s[j];
#pragma unroll
            for (int j = 0; j < 8; j++) Vt[(8 + j) * 136 + srow] = ub.s[j];
            __syncthreads();      // next tile ready
        }
    }

    // ---- merge the 4 K-group partials (overlay stage LDS as float scratch) ----
    cs += __shfl_xor(cs, 1);
    cs += __shfl_xor(cs, 2);

    float* mgf = (float*)&stage[0][0];   // 3 posts x 64 q x 18 fl + 8x16 cs slots
    int ql = qw * 32 + n;

    if (grp != 0) {
        float* dst = mgf + (size_t)(grp - 1) * 1152 + ql * 18;
#pragma unroll
        for (int j = 0; j < 4; j++) dst[4 * c + j]     = oacc[j];
#pragma unroll
        for (int j = 0; j < 4; j++) dst[8 + 4 * c + j] = oacc[4 + j];
        dst[16 + c] = oacc[8];
    }
    if (csp == 0) mgf[3456 + (grp * 2 + qw) * 16 + csd] = cs;
    __syncthreads();

    if (grp == 0) {
        float l = oacc[8];
        float o0[4], o1[4];
#pragma unroll
        for (int j = 0; j < 4; j++) { o0[j] = oacc[j]; o1[j] = oacc[4 + j]; }
#pragma unroll
        for (int p = 0; p < 3; p++) {
            const float* src = mgf + (size_t)p * 1152 + ql * 18;
#pragma unroll
            for (int j = 0; j < 4; j++) o0[j] += src[4 * c + j];
#pragma unroll
            for (int j = 0; j < 4; j++) o1[j] += src[8 + 4 * c + j];
            l += src[16 + c];
        }
        // V column-sum correction (the V*1 term) + l count (2048 keys)
#pragma unroll
        for (int s = 0; s < 8; s++) {
#pragma unroll
            for (int j = 0; j < 4; j++) o0[j] += mgf[3456 + s * 16 + 4 * c + j];
#pragma unroll
            for (int j = 0; j < 4; j++) o1[j] += mgf[3456 + s * 16 + 8 + 4 * c + j];
        }
        l += 2048.0f;

        float inv = 1.0f / l;
        float* orow = hb + base + (size_t)q * MM;
        f32x4 v0 = {o0[0] * inv, o0[1] * inv, o0[2] * inv, o0[3] * inv};
        f32x4 v1 = {o1[0] * inv, o1[1] * inv, o1[2] * inv, o1[3] * inv};
        *(f32x4*)(orow + 4 * c) = v0;
        *(f32x4*)(orow + 8 + 4 * c) = v1;
    }
}

// ---------------- Kernel 3: output projection ----------------
// 4 threads per (b,s) row (2 heads each), 2-step shuffle reduce. 256 blocks.
__global__ __launch_bounds__(128) void outproj_kernel(
    const float* __restrict__ hb, const float* __restrict__ wo,
    const float* __restrict__ bo, float* __restrict__ out)
{
    int tid = threadIdx.x;
    int row = blockIdx.x * 32 + (tid >> 2);   // b*S + s
    int hq = tid & 3;
    int b = row >> 11, s = row & 2047;

    float acc[16];
#pragma unroll
    for (int i = 0; i < 16; i++) acc[i] = 0.0f;

#pragma unroll
    for (int hi = 0; hi < 2; hi++) {
        int h = hq * 2 + hi;
        const float* hr = hb + ((size_t)(b * 8 + h) * SS + s) * MM;
        float hv[16];
        const f32x4* h4 = (const f32x4*)hr;
#pragma unroll
        for (int j = 0; j < 4; j++) {
            f32x4 tv = h4[j];
            hv[j*4+0] = tv[0]; hv[j*4+1] = tv[1]; hv[j*4+2] = tv[2]; hv[j*4+3] = tv[3];
        }
#pragma unroll
        for (int j = 0; j < 16; j++) {
            float hj = hv[j];
            const float* wr = wo + (((h << 4) + j) << 4);
#pragma unroll
            for (int i = 0; i < 16; i++) acc[i] = fmaf(hj, wr[i], acc[i]);
        }
    }

    // reduce the 4-lane group
#pragma unroll
    for (int i = 0; i < 16; i++) acc[i] += __shfl_xor(acc[i], 1);
#pragma unroll
    for (int i = 0; i < 16; i++) acc[i] += __shfl_xor(acc[i], 2);

    if (hq == 0) {
        float* op = out + (size_t)row * MM;
#pragma unroll
        for (int j = 0; j < 4; j++) {
            f32x4 v = {acc[4*j+0] + bo[4*j+0], acc[4*j+1] + bo[4*j+1],
                       acc[4*j+2] + bo[4*j+2], acc[4*j+3] + bo[4*j+3]};
            *(f32x4*)(op + 4*j) = v;
        }
    }
}

extern "C" void kernel_launch(void* const* d_in, const int* in_sizes, int n_in,
                              void* d_out, int out_size, void* d_ws, size_t ws_size,
                              hipStream_t stream) {
    const float* x  = (const float*)d_in[0];
    const float* wq = (const float*)d_in[1];
    const float* bq = (const float*)d_in[2];
    const float* wk = (const float*)d_in[3];
    const float* bk = (const float*)d_in[4];
    const float* wv = (const float*)d_in[5];
    const float* bv = (const float*)d_in[6];
    const float* wo = (const float*)d_in[7];
    const float* bo = (const float*)d_in[8];
    float* out = (float*)d_out;

    ushort* qb = (ushort*)d_ws;
    ushort* kb = qb + NQKV;
    ushort* vb = kb + NQKV;
    float*  hb = (float*)(vb + NQKV);   // 4 MB fp32 normalized head outputs

    proj_kernel<<<256, 256, 0, stream>>>(x, wq, bq, wk, bk, wv, bv, qb, kb, vb);
    attn_kernel<<<1024, 512, 0, stream>>>(qb, kb, vb, hb);
    outproj_kernel<<<256, 128, 0, stream>>>(hb, wo, bo, out);
}

// Round 13
// 50.795 us; speedup vs baseline: 1.8444x; 1.8444x over previous
//
#include <hip/hip_runtime.h>

#define BB 4
#define SS 2048
#define HH 8
#define MM 16

// 0.25 (= 1/sqrt(16)) * log2(e): fold softmax scale + exp->exp2 conversion into Q
#define QSCALE 0.36067376022224085f

typedef __attribute__((ext_vector_type(8)))  short short8;
typedef __attribute__((ext_vector_type(4)))  int   int4v;
typedef __attribute__((ext_vector_type(4)))  float f32x4;
typedef __attribute__((ext_vector_type(16))) float f32x16;

static constexpr size_t NQKV = (size_t)BB * HH * SS * MM;  // 1,048,576 elements

__device__ __forceinline__ int pk_bf16(float lo, float hi) {
    int r;
    asm("v_cvt_pk_bf16_f32 %0, %1, %2" : "=v"(r) : "v"(lo), "v"(hi));
    return r;
}

// ---------------- Kernel 1: Q/K/V projections (writes bf16, row-major) -------
__device__ __forceinline__ void proj16(const float xr[16], const float* __restrict__ w,
                                       const float* __restrict__ bias, int h, float out[16]) {
#pragma unroll
    for (int i = 0; i < 16; i++) out[i] = bias[(h << 4) + i];
#pragma unroll
    for (int j = 0; j < 16; j++) {
        float xj = xr[j];
        const float* wr = w + (((j * HH) + h) << 4);
#pragma unroll
        for (int i = 0; i < 16; i++) out[i] = fmaf(xj, wr[i], out[i]);
    }
}

__device__ __forceinline__ void pack_store(ushort* dst, const float o[16], float scale) {
    int4v w0, w1;
#pragma unroll
    for (int j = 0; j < 4; j++) w0[j] = pk_bf16(o[2*j] * scale,     o[2*j+1] * scale);
#pragma unroll
    for (int j = 0; j < 4; j++) w1[j] = pk_bf16(o[8+2*j] * scale,   o[8+2*j+1] * scale);
    int4v* p = (int4v*)dst;
    p[0] = w0; p[1] = w1;
}

__global__ __launch_bounds__(256) void proj_kernel(
    const float* __restrict__ x,
    const float* __restrict__ wq, const float* __restrict__ bq,
    const float* __restrict__ wk, const float* __restrict__ bk,
    const float* __restrict__ wv, const float* __restrict__ bv,
    ushort* __restrict__ qb, ushort* __restrict__ kb, ushort* __restrict__ vb)
{
    // 256 blocks: h = blockIdx>>5 (uniform -> scalar-cached weights)
    int h  = blockIdx.x >> 5;
    int bs = ((blockIdx.x & 31) << 8) + threadIdx.x;   // b*S + s
    int b  = bs >> 11;

    float xr[16];
    const float4* x4 = (const float4*)(x + (size_t)bs * MM);
#pragma unroll
    for (int j = 0; j < 4; j++) {
        float4 t = x4[j];
        xr[j*4+0] = t.x; xr[j*4+1] = t.y; xr[j*4+2] = t.z; xr[j*4+3] = t.w;
    }

    size_t orow = (((size_t)(b * HH + h) * SS) + (bs & 2047)) * MM;
    float o[16];

    proj16(xr, wq, bq, h, o);  pack_store(qb + orow, o, QSCALE);
    proj16(xr, wk, bk, h, o);  pack_store(kb + orow, o, 1.0f);
    proj16(xr, wv, bv, h, o);  pack_store(vb + orow, o, 1.0f);
}

// ---------------- Kernel 2: MFMA flash attention (R5 geometry, tuned) --------
// 512 blocks x 512 thr: 2 K-groups (grp, 1024 keys) x 4 q-waves (32 q each).
// Double-buffered 128-key tiles, reg-carry prefetch, ONE barrier per tile.
// K LDS: split-half layout (half c at c*1024 shorts, 16-B rows) -> fragment
// reads are contiguous 512 B, zero bank conflicts.
// V^T LDS: 32 rows x 136, cols XOR-swizzled by ((row>>3)&3)<<3 ushorts ->
// breaks the 4-way stride-272B conflict on vf ds_read_b128 (lanes n,n+8,+16,
// +24 spread to distinct 16-B blocks). Rows 16,20 = ones (l rows); rows
// 17-19/21-31 stale (their C rows 9-15 are never read).
// NUMERICS: PV feeds P-1 (p near 1 -> ~5x less bf16 abs err); V*1 term = per-
// tile V column sums (1 swizzled ds_read_b128/wave/tile) merged in epilogue;
// l = oacc[8] (Sum(p-1) via ones rows) + colsum-free count 2048.
// T5: s_setprio(1) around MFMAs.
__global__ __launch_bounds__(512) void attn_kernel(
    const ushort* __restrict__ qb, const ushort* __restrict__ kb,
    const ushort* __restrict__ vb, float* __restrict__ hb)
{
    __shared__ ushort Kl[2][2][2048];   // [grp][buf]: 2 halves x 128 rows x 8sh
    __shared__ ushort Vl[2][2][4352];   // [grp][buf]: 32 rows x 136, swizzled

    int tid = threadIdx.x;
    int grp = tid >> 8, t8 = tid & 255;
    int qw = (tid >> 6) & 3;
    int lane = tid & 63;
    int n = lane & 31, c = lane >> 5;

    // XCD-aware swizzle (512 = 8 x 64, bijective)
    int nb = ((blockIdx.x & 7) << 6) | (blockIdx.x >> 3);
    int bh = nb >> 4, qt = nb & 15;
    size_t base = (size_t)bh * SS * MM;
    const ushort* Qg = qb + base;
    const ushort* Kg = kb + base;
    const ushort* Vg = vb + base;

    int q = qt * 128 + qw * 32 + n;
    short8 qf = *(const short8*)(Qg + (size_t)q * MM + c * 8);

    // ones rows 16,20 (l accumulator rows), both buffers; swizzle-invariant
    // since the whole row is constant. Rows 17-19/21-31 stay stale (unread C).
    for (int i = t8; i < 136; i += 256) {
        Vl[grp][0][16 * 136 + i] = 0x3F80;
        Vl[grp][0][20 * 136 + i] = 0x3F80;
        Vl[grp][1][16 * 136 + i] = 0x3F80;
        Vl[grp][1][20 * 136 + i] = 0x3F80;
    }

    int k0 = grp * 1024;
    int srow = t8 >> 1, shalf = t8 & 1;    // thread stages 16 B of one key row
    int vswz0 = srow ^ (shalf == 0 ? 0 : 0);  // placeholder (row-dep below)

    // prologue: stage tile 0 into buf 0
    {
        int4v kw = *(const int4v*)(Kg + (size_t)(k0 + srow) * MM + shalf * 8);
        int4v vw = *(const int4v*)(Vg + (size_t)(k0 + srow) * MM + shalf * 8);
        *(int4v*)&Kl[grp][0][shalf * 1024 + srow * 8] = kw;
        union { int4v v; ushort s[8]; } vu; vu.v = vw;
#pragma unroll
        for (int j = 0; j < 8; j++) {
            int row = 8 * shalf + j;
            Vl[grp][0][row * 136 + (srow ^ (((row >> 3) & 3) << 3))] = vu.s[j];
        }
    }
    __syncthreads();

    f32x16 oacc = 0;
    const f32x16 zacc = 0;
    float cs = 0.0f;                 // V column-sum partial
    int csd = lane >> 2, csp = lane & 3;
    int vsw_n  = ((n >> 3) & 3) << 3;      // read swizzle for V^T row n
    int vsw_cs = ((csd >> 3) & 3) << 3;    // read swizzle for colsum row csd

    for (int t = 0; t < 8; t++) {
        int cur = t & 1;
        const ushort* Klp = &Kl[grp][cur][0];
        const ushort* Vt  = &Vl[grp][cur][0];

        // prefetch next tile into regs (8 VGPRs); hides under compute
        int4v kw, vw;
        if (t != 7) {
            kw = *(const int4v*)(Kg + (size_t)(k0 + (t + 1) * 128 + srow) * MM + shalf * 8);
            vw = *(const int4v*)(Vg + (size_t)(k0 + (t + 1) * 128 + srow) * MM + shalf * 8);
        }

#pragma unroll
        for (int sub = 0; sub < 4; sub++) {
            short8 kf  = *(const short8*)&Klp[c * 1024 + (sub * 32 + n) * 8];
            short8 vf1 = *(const short8*)&Vt[n * 136 + ((sub * 32 + c * 8) ^ vsw_n)];
            short8 vf2 = *(const short8*)&Vt[n * 136 + ((sub * 32 + 16 + c * 8) ^ vsw_n)];

            __builtin_amdgcn_s_setprio(1);
            f32x16 s = __builtin_amdgcn_mfma_f32_32x32x16_bf16(kf, qf, zacc, 0, 0, 0);
            __builtin_amdgcn_s_setprio(0);

            float p0 = __builtin_amdgcn_exp2f(s[0])  - 1.0f;
            float p1 = __builtin_amdgcn_exp2f(s[1])  - 1.0f;
            float p2 = __builtin_amdgcn_exp2f(s[2])  - 1.0f;
            float p3 = __builtin_amdgcn_exp2f(s[3])  - 1.0f;
            float p4 = __builtin_amdgcn_exp2f(s[4])  - 1.0f;
            float p5 = __builtin_amdgcn_exp2f(s[5])  - 1.0f;
            float p6 = __builtin_amdgcn_exp2f(s[6])  - 1.0f;
            float p7 = __builtin_amdgcn_exp2f(s[7])  - 1.0f;
            int a0 = pk_bf16(p0, p1), a1 = pk_bf16(p2, p3);
            int a2 = pk_bf16(p4, p5), a3 = pk_bf16(p6, p7);
            int w0 = a0, w2 = a2;
            asm("v_permlane32_swap_b32 %0, %1" : "+v"(w0), "+v"(w2));
            int w1 = a1, w3 = a3;
            asm("v_permlane32_swap_b32 %0, %1" : "+v"(w1), "+v"(w3));
            int4v bi1 = {w0, w1, w2, w3};
            __builtin_amdgcn_s_setprio(1);
            oacc = __builtin_amdgcn_mfma_f32_32x32x16_bf16(
                vf1, __builtin_bit_cast(short8, bi1), oacc, 0, 0, 0);
            __builtin_amdgcn_s_setprio(0);

            float p8  = __builtin_amdgcn_exp2f(s[8])  - 1.0f;
            float p9  = __builtin_amdgcn_exp2f(s[9])  - 1.0f;
            float p10 = __builtin_amdgcn_exp2f(s[10]) - 1.0f;
            float p11 = __builtin_amdgcn_exp2f(s[11]) - 1.0f;
            float p12 = __builtin_amdgcn_exp2f(s[12]) - 1.0f;
            float p13 = __builtin_amdgcn_exp2f(s[13]) - 1.0f;
            float p14 = __builtin_amdgcn_exp2f(s[14]) - 1.0f;
            float p15 = __builtin_amdgcn_exp2f(s[15]) - 1.0f;
            int a4 = pk_bf16(p8,  p9),  a5 = pk_bf16(p10, p11);
            int a6 = pk_bf16(p12, p13), a7 = pk_bf16(p14, p15);
            int u0 = a4, u2 = a6;
            asm("v_permlane32_swap_b32 %0, %1" : "+v"(u0), "+v"(u2));
            int u1 = a5, u3 = a7;
            asm("v_permlane32_swap_b32 %0, %1" : "+v"(u1), "+v"(u3));
            int4v bi2 = {u0, u1, u2, u3};
            __builtin_amdgcn_s_setprio(1);
            oacc = __builtin_amdgcn_mfma_f32_32x32x16_bf16(
                vf2, __builtin_bit_cast(short8, bi2), oacc, 0, 0, 0);
            __builtin_amdgcn_s_setprio(0);
        }

        // per-tile V column sum: wave qw covers keys qw*32 + csp*8 .. +7
        {
            int4v u = *(const int4v*)&Vt[csd * 136 + ((qw * 32 + csp * 8) ^ vsw_cs)];
#pragma unroll
            for (int j = 0; j < 4; j++) {
                cs += __builtin_bit_cast(float, u[j] << 16);
                cs += __builtin_bit_cast(float, (int)(u[j] & 0xFFFF0000));
            }
        }

        // write next tile into the other buffer (its readers all passed the
        // previous barrier) -> one barrier per tile
        if (t != 7) {
            *(int4v*)&Kl[grp][cur ^ 1][shalf * 1024 + srow * 8] = kw;
            union { int4v v; ushort s[8]; } vu; vu.v = vw;
#pragma unroll
            for (int j = 0; j < 8; j++) {
                int row = 8 * shalf + j;
                Vl[grp][cur ^ 1][row * 136 + (srow ^ (((row >> 3) & 3) << 3))] = vu.s[j];
            }
        }
        __syncthreads();
    }

    // ---- merge the 2 K-group partials (overlay Kl as float scratch) ----
    cs += __shfl_xor(cs, 1);
    cs += __shfl_xor(cs, 2);

    float* mgf = (float*)&Kl[0][0][0];   // 128 q x 18 fl (2304) + 8x16 cs slots
    int ql = qw * 32 + n;

    if (grp == 1) {
        float* dst = mgf + ql * 18;
#pragma unroll
        for (int j = 0; j < 4; j++) dst[4 * c + j]     = oacc[j];
#pragma unroll
        for (int j = 0; j < 4; j++) dst[8 + 4 * c + j] = oacc[4 + j];
        dst[16 + c] = oacc[8];
    }
    if (csp == 0) mgf[2304 + (grp * 4 + qw) * 16 + csd] = cs;
    __syncthreads();

    if (grp == 0) {
        const float* src = mgf + ql * 18;
        float l = oacc[8] + src[16 + c] + 2048.0f;
        float o0[4], o1[4];
#pragma unroll
        for (int j = 0; j < 4; j++) o0[j] = oacc[j]     + src[4 * c + j];
#pragma unroll
        for (int j = 0; j < 4; j++) o1[j] = oacc[4 + j] + src[8 + 4 * c + j];
        // V column-sum correction (the V*1 term), 8 (grp,qw) slots
#pragma unroll
        for (int s2 = 0; s2 < 8; s2++) {
#pragma unroll
            for (int j = 0; j < 4; j++) o0[j] += mgf[2304 + s2 * 16 + 4 * c + j];
#pragma unroll
            for (int j = 0; j < 4; j++) o1[j] += mgf[2304 + s2 * 16 + 8 + 4 * c + j];
        }

        float inv = 1.0f / l;
        float* orow = hb + base + (size_t)q * MM;
        f32x4 v0 = {o0[0] * inv, o0[1] * inv, o0[2] * inv, o0[3] * inv};
        f32x4 v1 = {o1[0] * inv, o1[1] * inv, o1[2] * inv, o1[3] * inv};
        *(f32x4*)(orow + 4 * c) = v0;
        *(f32x4*)(orow + 8 + 4 * c) = v1;
    }
}

// ---------------- Kernel 3: output projection ----------------
// 4 threads per (b,s) row (2 heads each), 2-step shuffle reduce. 256 blocks.
__global__ __launch_bounds__(128) void outproj_kernel(
    const float* __restrict__ hb, const float* __restrict__ wo,
    const float* __restrict__ bo, float* __restrict__ out)
{
    int tid = threadIdx.x;
    int row = blockIdx.x * 32 + (tid >> 2);   // b*S + s
    int hq = tid & 3;
    int b = row >> 11, s = row & 2047;

    float acc[16];
#pragma unroll
    for (int i = 0; i < 16; i++) acc[i] = 0.0f;

#pragma unroll
    for (int hi = 0; hi < 2; hi++) {
        int h = hq * 2 + hi;
        const float* hr = hb + ((size_t)(b * 8 + h) * SS + s) * MM;
        float hv[16];
        const f32x4* h4 = (const f32x4*)hr;
#pragma unroll
        for (int j = 0; j < 4; j++) {
            f32x4 tv = h4[j];
            hv[j*4+0] = tv[0]; hv[j*4+1] = tv[1]; hv[j*4+2] = tv[2]; hv[j*4+3] = tv[3];
        }
#pragma unroll
        for (int j = 0; j < 16; j++) {
            float hj = hv[j];
            const float* wr = wo + (((h << 4) + j) << 4);
#pragma unroll
            for (int i = 0; i < 16; i++) acc[i] = fmaf(hj, wr[i], acc[i]);
        }
    }

#pragma unroll
    for (int i = 0; i < 16; i++) acc[i] += __shfl_xor(acc[i], 1);
#pragma unroll
    for (int i = 0; i < 16; i++) acc[i] += __shfl_xor(acc[i], 2);

    if (hq == 0) {
        float* op = out + (size_t)row * MM;
#pragma unroll
        for (int j = 0; j < 4; j++) {
            f32x4 v = {acc[4*j+0] + bo[4*j+0], acc[4*j+1] + bo[4*j+1],
                       acc[4*j+2] + bo[4*j+2], acc[4*j+3] + bo[4*j+3]};
            *(f32x4*)(op + 4*j) = v;
        }
    }
}

extern "C" void kernel_launch(void* const* d_in, const int* in_sizes, int n_in,
                              void* d_out, int out_size, void* d_ws, size_t ws_size,
                              hipStream_t stream) {
    const float* x  = (const float*)d_in[0];
    const float* wq = (const float*)d_in[1];
    const float* bq = (const float*)d_in[2];
    const float* wk = (const float*)d_in[3];
    const float* bk = (const float*)d_in[4];
    const float* wv = (const float*)d_in[5];
    const float* bv = (const float*)d_in[6];
    const float* wo = (const float*)d_in[7];
    const float* bo = (const float*)d_in[8];
    float* out = (float*)d_out;

    ushort* qb = (ushort*)d_ws;
    ushort* kb = qb + NQKV;
    ushort* vb = kb + NQKV;
    float*  hb = (float*)(vb + NQKV);   // 4 MB fp32 normalized head outputs

    proj_kernel<<<256, 256, 0, stream>>>(x, wq, bq, wk, bk, wv, bv, qb, kb, vb);
    attn_kernel<<<512, 512, 0, stream>>>(qb, kb, vb, hb);
    outproj_kernel<<<256, 128, 0, stream>>>(hb, wo, bo, out);
}